// Round 9
// baseline (274.959 us; speedup 1.0000x reference)
//
#include <hip/hip_runtime.h>
#include <hip/hip_fp16.h>
#include <stdint.h>

// Problem constants: B=8, H=W=128, C=F=256, K=7, PAD=3, rs=128
typedef _Float16 half8 __attribute__((ext_vector_type(8)));   // 8 fp16 = 4 VGPR (MFMA A/B frag)
typedef _Float16 half2v __attribute__((ext_vector_type(2)));  // packed fp16 pair
typedef __attribute__((ext_vector_type(4))) float f32x4;      // MFMA C/D frag

__device__ __forceinline__ unsigned short f2h(float f) {      // RNE fp32->fp16
  __half h = __float2half(f);
  unsigned short u; __builtin_memcpy(&u, &h, 2); return u;
}
__device__ __forceinline__ unsigned pk2h(float a, float b) {  // RTZ packed pair (staging only)
  auto v = __builtin_amdgcn_cvt_pkrtz(a, b);
  unsigned u; __builtin_memcpy(&u, &v, 4); return u;
}
__device__ __forceinline__ half2v h2cast(unsigned u) {
  half2v v; __builtin_memcpy(&v, &u, 4); return v;
}

#if __has_builtin(__builtin_amdgcn_fdot2)
__device__ __forceinline__ float dot2(half2v a, half2v b, float c) {
  return __builtin_amdgcn_fdot2(a, b, c, false);
}
#else
__device__ __forceinline__ float dot2(half2v a, half2v b, float c) {
  return c + (float)a[0] * (float)b[0] + (float)a[1] * (float)b[1];
}
#endif

// async global->LDS, 16B per lane; lds dest = wave-uniform base + lane*16
__device__ __forceinline__ void gl_lds16(const void* g, void* l) {
  __builtin_amdgcn_global_load_lds(
      (const __attribute__((address_space(1))) void*)g,
      (__attribute__((address_space(3))) void*)l, 16, 0, 0);
}

// ---------------- Kernel 0+1 merged: x fp32->fp16, and weight transpose+cvt ----------
__global__ __launch_bounds__(256) void prep(const float* __restrict__ x,
                                            const float* __restrict__ Wq,
                                            const float* __restrict__ Wk,
                                            const float* __restrict__ Wv,
                                            unsigned short* __restrict__ xh,
                                            unsigned short* __restrict__ Wb) {
  const int bid = blockIdx.x;
  if (bid < 16384) {
    const size_t i = ((size_t)bid * 256 + threadIdx.x) * 8;
    float4 a = *(const float4*)&x[i];
    float4 b = *(const float4*)&x[i + 4];
    uint4 o;
    o.x = pk2h(a.x, a.y); o.y = pk2h(a.z, a.w);
    o.z = pk2h(b.x, b.y); o.w = pk2h(b.z, b.w);
    *(uint4*)&xh[i] = o;
  } else {
    const int e = bid - 16384;
    const int w = e >> 8;
    const int n = e & 255;
    const float* W = (w == 0) ? Wq : ((w == 1) ? Wk : Wv);
    const int k = threadIdx.x;
    Wb[(size_t)e * 256 + k] = f2h(W[(size_t)k * 256 + n]);
  }
}

// ---------------- Kernel 2: fused QKV GEMM (fp16 MFMA, global_load_lds staging) ----------
__global__ __launch_bounds__(256) void qkv_gemm(const unsigned short* __restrict__ xh,
                                                const unsigned short* __restrict__ Wb,
                                                unsigned short* __restrict__ qkv) {
  __shared__ unsigned char ldsb[32768];

  const int tid = threadIdx.x;
  const int l = tid & 63, l15 = l & 15, l4 = l >> 4;
  const int wv = tid >> 6, wr = wv >> 1, wc = wv & 1;

  // XCD-aware chunked swizzle: 6144 blocks, 8 XCDs, 768 per XCD (bijective).
  const int pid = blockIdx.x;
  const int cid = (pid & 7) * 768 + (pid >> 3);
  const int by = cid / 6;
  const int bx = cid - by * 6;
  const size_t row0 = (size_t)by * 128;
  const int n0 = bx * 128;

  const int rbase0 = wv * 32, rbase1 = wv * 32 + 16;
  const int rA0 = rbase0 + (l >> 2), rA1 = rbase1 + (l >> 2);
  const int q0 = (l & 3) ^ ((rA0 >> 1) & 3), q1 = (l & 3) ^ ((rA1 >> 1) & 3);
  const unsigned short* gA0 = xh + (row0 + rA0) * 256 + q0 * 8;
  const unsigned short* gA1 = xh + (row0 + rA1) * 256 + q1 * 8;
  const unsigned short* gB0 = Wb + (size_t)(n0 + rA0) * 256 + q0 * 8;
  const unsigned short* gB1 = Wb + (size_t)(n0 + rA1) * 256 + q1 * 8;

  f32x4 acc[4][4] = {};

  auto stage = [&](int s, int d) {
    gl_lds16(gA0 + s * 32, &ldsb[d * 8192 + rbase0 * 64]);
    gl_lds16(gA1 + s * 32, &ldsb[d * 8192 + rbase1 * 64]);
    gl_lds16(gB0 + s * 32, &ldsb[16384 + d * 8192 + rbase0 * 64]);
    gl_lds16(gB1 + s * 32, &ldsb[16384 + d * 8192 + rbase1 * 64]);
  };

  stage(0, 0);
  __syncthreads();

  for (int s = 0; s < 8; ++s) {
    const int d = s & 1;
    if (s < 7) stage(s + 1, d ^ 1);
    half8 af[4], bf[4];
#pragma unroll
    for (int m = 0; m < 4; ++m) {
      const int r = wr * 64 + m * 16 + l15;
      af[m] = *(const half8*)&ldsb[d * 8192 + r * 64 + ((l4 ^ ((r >> 1) & 3)) * 16)];
    }
#pragma unroll
    for (int n = 0; n < 4; ++n) {
      const int r = wc * 64 + n * 16 + l15;
      bf[n] = *(const half8*)&ldsb[16384 + d * 8192 + r * 64 + ((l4 ^ ((r >> 1) & 3)) * 16)];
    }
#pragma unroll
    for (int n = 0; n < 4; ++n)
#pragma unroll
      for (int m = 0; m < 4; ++m)
        acc[m][n] = __builtin_amdgcn_mfma_f32_16x16x32_f16(af[m], bf[n], acc[m][n], 0, 0, 0);
    __syncthreads();
  }

  // Epilogue: C/D mapping col=lane&15, row=(lane>>4)*4+reg (m89-verified)
#pragma unroll
  for (int m = 0; m < 4; ++m)
#pragma unroll
    for (int n = 0; n < 4; ++n) {
      const int ng = n0 + wc * 64 + n * 16 + l15;
      unsigned short* op = qkv + (size_t)(ng >> 8) * 33554432 + (ng & 255);
#pragma unroll
      for (int r = 0; r < 4; ++r) {
        const size_t grow = row0 + wr * 64 + m * 16 + l4 * 4 + r;
        op[grow * 256] = f2h(acc[m][n][r]);
      }
    }
}

// ---------------- Kernel 2b: per-pixel relative-position projections ----------------
__global__ __launch_bounds__(256) void qrel(const unsigned short* __restrict__ q,
                                            const float* __restrict__ relx,
                                            const float* __restrict__ rely,
                                            unsigned short* __restrict__ qr) {
  __shared__ unsigned wpk[896];  // [0..447] x-pairs, [448..895] y-pairs; wpk[c2*7+j]
  for (int i = threadIdx.x; i < 896; i += 256) {
    const int hf = (i >= 448) ? 1 : 0;
    const int r = i - hf * 448;
    const int c2 = r / 7, j = r - c2 * 7;
    const float* R = hf ? rely : relx;
    wpk[i] = pk2h(R[(2 * c2) * 7 + j], R[(2 * c2 + 1) * 7 + j]);
  }
  __syncthreads();
  const size_t pix = (size_t)blockIdx.x * 256 + threadIdx.x;
  const uint4* qp = (const uint4*)(q + pix * 256);  // 32 uint4 = 256 fp16 channels
  float ax[7] = {0, 0, 0, 0, 0, 0, 0}, ay[7] = {0, 0, 0, 0, 0, 0, 0};
#pragma unroll
  for (int g = 0; g < 32; ++g) {
    const uint4 u = qp[g];
    const int c2b = (g & 15) * 4;
    if (g < 16) {
#pragma unroll
      for (int j = 0; j < 7; ++j) {
        float s = ax[j];
        s = dot2(h2cast(u.x), h2cast(wpk[(c2b + 0) * 7 + j]), s);
        s = dot2(h2cast(u.y), h2cast(wpk[(c2b + 1) * 7 + j]), s);
        s = dot2(h2cast(u.z), h2cast(wpk[(c2b + 2) * 7 + j]), s);
        s = dot2(h2cast(u.w), h2cast(wpk[(c2b + 3) * 7 + j]), s);
        ax[j] = s;
      }
    } else {
#pragma unroll
      for (int j = 0; j < 7; ++j) {
        float s = ay[j];
        s = dot2(h2cast(u.x), h2cast(wpk[448 + (c2b + 0) * 7 + j]), s);
        s = dot2(h2cast(u.y), h2cast(wpk[448 + (c2b + 1) * 7 + j]), s);
        s = dot2(h2cast(u.z), h2cast(wpk[448 + (c2b + 2) * 7 + j]), s);
        s = dot2(h2cast(u.w), h2cast(wpk[448 + (c2b + 3) * 7 + j]), s);
        ay[j] = s;
      }
    }
  }
  uint4 o0, o1;
  o0.x = pk2h(ax[0], ax[1]); o0.y = pk2h(ax[2], ax[3]);
  o0.z = pk2h(ax[4], ax[5]); o0.w = pk2h(ax[6], ay[0]);
  o1.x = pk2h(ay[1], ay[2]); o1.y = pk2h(ay[3], ay[4]);
  o1.z = pk2h(ay[5], ay[6]); o1.w = 0;
  uint4* dst = (uint4*)(qr + pix * 512);
  dst[0] = o0; dst[1] = o1;
}

// ---------------- Kernel 3: fused windowed attention ----------------
// v10 = v9 phase A (MFMA, verified) + PAIR-SHARED phase B.
// Corrected LDS arithmetic: phase-B reads 3.29 GB total from LDS (131072 px x 49 x
// 64 B x 8 chunks) = ~63us of b128 pipe time (85 B/cyc/CU, m134) — half the 157us
// kernel. Lever: vertical-pair sharing (x0.571 traffic, proven numerically in v4)
// WITHOUT v4's thread-count collapse: thread = (pixel-pair, plane-quarter q).
// 512 threads unchanged: q=tid>>7 (8ch plane), pa=(tid>>5)&3 (row pair 2pa,2pa+1),
// pc=tid&31 (col). Per chunk: pair's 8 shared halo rows x 7 cols x 1 plane = 56 b128
// (vs 98) serving 2 px x 8 ch. Lanes read contiguous slots at 16B stride (v3-proven
// 0-conflict). Softmax per pair done sequentially (A then B, sc[49] storage reused,
// peak regs ~120); weights packed phA|phB<<16, broadcast via half2v{pp[i],pp[i]}
// (op_sel-foldable). Phase A / P-handoff / staging / tile byte-identical to v9.
__global__ __launch_bounds__(512, 2) void attn(const unsigned short* __restrict__ qkv,
                                               const float* __restrict__ bias,
                                               const unsigned short* __restrict__ qrelb,
                                               float* __restrict__ out) {
  __shared__ unsigned short kv[2][4][4256];  // 2 buf x 4 planes x 532 slots*8 = 68096 B

  const int tid = threadIdx.x;               // 0..511
  const int wv = tid >> 6;                   // wave 0..7
  const int lo = tid & 15, hi = (tid >> 4) & 3;
  const int rp = wv >> 1;                    // phase-A row-pair 0..3
  const int ch16 = (wv & 1) * 16;            // phase-A column-half base

  // phase-B pair mapping
  const int q = tid >> 7;                    // plane-quarter 0..3 (ch q*8..q*8+7)
  const int pa = (tid >> 5) & 3;             // pair-row (pixel rows 2pa, 2pa+1)
  const int pc = tid & 31;                   // col

  const int pid = blockIdx.x;
  const int cid = (pid & 7) * 64 + (pid >> 3);   // XCD-chunked (512 = 8*64, bijective)
  const int ht = cid & 15, wt = (cid >> 4) & 3, b = cid >> 6;

  const int hA = ht * 8 + 2 * pa, wA = wt * 32 + pc;
  const size_t pixA = (size_t)((b * 128 + hA) * 128 + wA);
  const size_t pixB = pixA + 128;
  const int pxA = 2 * pa * 32 + pc;          // pixel index within tile
  const int pxB = pxA + 32;

  const unsigned short* qb = qkv;
  const unsigned short* kb = qkv + 33554432;
  const unsigned short* vb = qkv + 67108864;

  // staging geometry: 532 halo slots; thread covers slot tid, and tid+512 (<532)
  const int pr0 = tid / 38, pc0 = tid - pr0 * 38;
  const int gh0 = ht * 8 + pr0 - 3, gw0 = wt * 32 + pc0 - 3;
  const bool ok0 = ((unsigned)gh0 < 128u) && ((unsigned)gw0 < 128u);
  const long long go0 = ((long long)((b * 128 + gh0) * 128 + gw0)) * 256;  // shorts

  const int p1 = tid + 512;
  const int pr1 = p1 / 38, pc1 = p1 - pr1 * 38;
  const int gh1 = ht * 8 + pr1 - 3, gw1 = wt * 32 + pc1 - 3;
  const bool ok1 = (p1 < 532) && ((unsigned)gh1 < 128u) && ((unsigned)gw1 < 128u);
  const long long go1 = ((long long)((b * 128 + gh1) * 128 + gw1)) * 256;

  // async stage of chunk c (4 planes) into buffer d (no registers, no waits)
  auto stage = [&](const unsigned short* base, int c, int d) {
#pragma unroll
    for (int g = 0; g < 4; ++g) {
      if (ok0) gl_lds16(base + go0 + c * 32 + g * 8, &kv[d][g][wv * 512]);
      if (ok1) gl_lds16(base + go1 + c * 32 + g * 8, &kv[d][g][4096]);
    }
  };

  // zero OOB halo slots (both buffers); needed before phase A and again before phase B
  auto zero_oob = [&]() {
    const uint4 z = make_uint4(0u, 0u, 0u, 0u);
    for (int p = tid; p < 532; p += 512) {
      const int pr = p / 38, pcx = p - pr * 38;
      const int gh = ht * 8 + pr - 3, gw = wt * 32 + pcx - 3;
      if (!((unsigned)gh < 128u && (unsigned)gw < 128u)) {
#pragma unroll
        for (int d = 0; d < 2; ++d)
#pragma unroll
          for (int g = 0; g < 4; ++g)
            *(uint4*)&kv[d][g][p * 8] = z;
      }
    }
  };

  zero_oob();
  stage(kb, 0, 0);
  __syncthreads();   // implicit vmcnt(0): chunk-0 K staged + OOB zeros visible

  // ---- Phase A (MFMA, v8/v9-verified): acc[g][t] = S[16q][16keys of tile t] ----
  int slot0[7];
#pragma unroll
  for (int t = 0; t < 7; ++t) {
    const int p = t * 16 + lo;
    const int ur = p / 14, uc = p - ur * 14;
    slot0[t] = (2 * rp + ur) * 38 + ch16 + uc;
  }
  const size_t qpix =
      (size_t)((b * 128 + ht * 8 + 2 * rp + (lo >> 3)) * 128 + wt * 32 + ch16 + (lo & 7));
  const unsigned short* qlane = qb + qpix * 256 + hi * 8;

  f32x4 acc[2][7] = {};

  for (int s = 0; s < 8; ++s) {
    const int d = s & 1;
    if (s < 7) stage(kb, s + 1, d ^ 1);
    half8 qf[2];
#pragma unroll
    for (int g = 0; g < 2; ++g)
      qf[g] = *(const half8*)(qlane + (size_t)g * 2048 + s * 32);  // +8 px per group
    const unsigned short* kpl = &kv[d][hi][0];
    __builtin_amdgcn_s_setprio(1);
#pragma unroll
    for (int t = 0; t < 7; ++t) {
      const unsigned short* kt = kpl + slot0[t] * 8;
#pragma unroll
      for (int g = 0; g < 2; ++g) {
        const half8 kf = *(const half8*)(kt + g * 64);
        acc[g][t] = __builtin_amdgcn_mfma_f32_16x16x32_f16(qf[g], kf, acc[g][t], 0, 0, 0);
      }
    }
    __builtin_amdgcn_s_setprio(0);
    __syncthreads();
  }

  // ---- P hand-off: scatter valid-window scores (f32) into P-buffer aliasing kv ----
  float* pbuf = (float*)&kv[0][0][0];  // 256 rows x 52 f32 = 53248 B <= 68096 B
#pragma unroll
  for (int t = 0; t < 7; ++t) {
    const int p = t * 16 + lo;
    const int ur = p / 14, uc = p - ur * 14;
#pragma unroll
    for (int r = 0; r < 4; ++r) {
      const int qq = hi * 4 + r;
      const int di = ur - (qq >> 3), dj = uc - (qq & 7);
      if (((unsigned)di < 7u) && ((unsigned)dj < 7u)) {
        const int pslot = di * 7 + dj;
#pragma unroll
        for (int g = 0; g < 2; ++g) {
          const int prow_ = (2 * rp + (qq >> 3)) * 32 + ch16 + 8 * g + (qq & 7);
          pbuf[prow_ * 52 + pslot] = acc[g][t][r];
        }
      }
    }
  }
  __syncthreads();

  // ---- pair softmax: pixel A -> pwp low16, pixel B -> pwp high16 ----
  unsigned pwp[49];
  {
    float sc[49];
    const float* prow = pbuf + pxA * 52;
#pragma unroll
    for (int k = 0; k < 12; ++k) {
      const float4 v = ((const float4*)prow)[k];
      sc[k * 4 + 0] = v.x; sc[k * 4 + 1] = v.y;
      sc[k * 4 + 2] = v.z; sc[k * 4 + 3] = v.w;
    }
    sc[48] = prow[48];
    const uint4* rpq = (const uint4*)(qrelb + pixA * 512);
    uint4 r0 = rpq[0], r1 = rpq[1];
    half2v a0 = h2cast(r0.x), a1 = h2cast(r0.y), a2 = h2cast(r0.z), a3 = h2cast(r0.w);
    half2v b0 = h2cast(r1.x), b1 = h2cast(r1.y), b2 = h2cast(r1.z);
    float qx[7] = {a0[0], a0[1], a1[0], a1[1], a2[0], a2[1], a3[0]};
    float qy[7] = {a3[1], b0[0], b0[1], b1[0], b1[1], b2[0], b2[1]};
#pragma unroll
    for (int i = 0; i < 7; ++i)
#pragma unroll
      for (int j = 0; j < 7; ++j) sc[i * 7 + j] += qx[j] + qy[i];
    float mx = sc[0];
#pragma unroll
    for (int t = 1; t < 49; ++t) mx = fmaxf(mx, sc[t]);
    float sum = 0.0f;
#pragma unroll
    for (int t = 0; t < 49; ++t) {
      float e = __expf(sc[t] - mx);
      sc[t] = e;
      sum += e;
    }
    const float invs = 1.0f / sum;
#pragma unroll
    for (int t = 0; t < 49; ++t) pwp[t] = (unsigned)f2h(sc[t] * invs);
  }
  {
    float sc[49];
    const float* prow = pbuf + pxB * 52;
#pragma unroll
    for (int k = 0; k < 12; ++k) {
      const float4 v = ((const float4*)prow)[k];
      sc[k * 4 + 0] = v.x; sc[k * 4 + 1] = v.y;
      sc[k * 4 + 2] = v.z; sc[k * 4 + 3] = v.w;
    }
    sc[48] = prow[48];
    const uint4* rpq = (const uint4*)(qrelb + pixB * 512);
    uint4 r0 = rpq[0], r1 = rpq[1];
    half2v a0 = h2cast(r0.x), a1 = h2cast(r0.y), a2 = h2cast(r0.z), a3 = h2cast(r0.w);
    half2v b0 = h2cast(r1.x), b1 = h2cast(r1.y), b2 = h2cast(r1.z);
    float qx[7] = {a0[0], a0[1], a1[0], a1[1], a2[0], a2[1], a3[0]};
    float qy[7] = {a3[1], b0[0], b0[1], b1[0], b1[1], b2[0], b2[1]};
#pragma unroll
    for (int i = 0; i < 7; ++i)
#pragma unroll
      for (int j = 0; j < 7; ++j) sc[i * 7 + j] += qx[j] + qy[i];
    float mx = sc[0];
#pragma unroll
    for (int t = 1; t < 49; ++t) mx = fmaxf(mx, sc[t]);
    float sum = 0.0f;
#pragma unroll
    for (int t = 0; t < 49; ++t) {
      float e = __expf(sc[t] - mx);
      sc[t] = e;
      sum += e;
    }
    const float invs = 1.0f / sum;
#pragma unroll
    for (int t = 0; t < 49; ++t) pwp[t] |= ((unsigned)f2h(sc[t] * invs)) << 16;
  }
  __syncthreads();   // all pbuf reads done before kv is clobbered below

  // restore kv for phase B: re-zero OOB slots, stage V chunk 0 into buf 0
  zero_oob();
  stage(vb, 0, 0);
  __syncthreads();   // vmcnt(0): V chunk 0 + re-zeroed OOB visible

  // ---- Phase B (pair-shared): thread computes 2 px x 8 ch (plane q) ----
  for (int s = 0; s < 8; ++s) {
    const int d = s & 1;
    const int f0 = s * 32 + q * 8;
    if (s < 7) stage(vb, s + 1, d ^ 1);
    half2v accA[4], accB[4];
#pragma unroll
    for (int a2 = 0; a2 < 4; ++a2) {
      accA[a2] = half2v{(_Float16)0, (_Float16)0};
      accB[a2] = half2v{(_Float16)0, (_Float16)0};
    }
    __builtin_amdgcn_s_setprio(1);
#pragma unroll
    for (int u = 0; u < 8; ++u) {      // shared halo row 2pa+u; A taps u<7, B taps u>=1
      const int rb8 = ((2 * pa + u) * 38 + pc) * 8;
      uint4 ua[7];
#pragma unroll
      for (int j = 0; j < 7; ++j) ua[j] = *(const uint4*)&kv[d][q][rb8 + j * 8];
#pragma unroll
      for (int j = 0; j < 7; ++j) {
        if (u < 7) {
          const half2v pp = h2cast(pwp[u * 7 + j]);
          const half2v p2 = half2v{pp[0], pp[0]};
          accA[0] += p2 * h2cast(ua[j].x);
          accA[1] += p2 * h2cast(ua[j].y);
          accA[2] += p2 * h2cast(ua[j].z);
          accA[3] += p2 * h2cast(ua[j].w);
        }
        if (u >= 1) {
          const half2v pp = h2cast(pwp[(u - 1) * 7 + j]);
          const half2v p2 = half2v{pp[1], pp[1]};
          accB[0] += p2 * h2cast(ua[j].x);
          accB[1] += p2 * h2cast(ua[j].y);
          accB[2] += p2 * h2cast(ua[j].z);
          accB[3] += p2 * h2cast(ua[j].w);
        }
      }
    }
    __builtin_amdgcn_s_setprio(0);
#pragma unroll
    for (int fq = 0; fq < 2; ++fq) {
      float4 bv = *(const float4*)&bias[f0 + fq * 4];
      float4 oA, oB;
      oA.x = (float)accA[fq * 2 + 0][0] + bv.x;
      oA.y = (float)accA[fq * 2 + 0][1] + bv.y;
      oA.z = (float)accA[fq * 2 + 1][0] + bv.z;
      oA.w = (float)accA[fq * 2 + 1][1] + bv.w;
      oB.x = (float)accB[fq * 2 + 0][0] + bv.x;
      oB.y = (float)accB[fq * 2 + 0][1] + bv.y;
      oB.z = (float)accB[fq * 2 + 1][0] + bv.z;
      oB.w = (float)accB[fq * 2 + 1][1] + bv.w;
      *(float4*)&out[pixA * 256 + f0 + fq * 4] = oA;
      *(float4*)&out[pixB * 256 + f0 + fq * 4] = oB;
    }
    if (s < 7) __syncthreads();
  }
}

extern "C" void kernel_launch(void* const* d_in, const int* in_sizes, int n_in,
                              void* d_out, int out_size, void* d_ws, size_t ws_size,
                              hipStream_t stream) {
  const float* x = (const float*)d_in[0];
  const float* Wq = (const float*)d_in[1];
  const float* Wk = (const float*)d_in[2];
  const float* Wv = (const float*)d_in[3];
  const float* relx = (const float*)d_in[4];
  const float* rely = (const float*)d_in[5];
  const float* bias = (const float*)d_in[6];
  float* out = (float*)d_out;

  // d_out doubles as scratch: xh (fp16 x) dead after qkv_gemm; qrel writes 32 B into each
  // pixel's out slot head, read by attn before that slot is overwritten.
  unsigned short* xh = (unsigned short*)d_out;
  unsigned short* qrl = (unsigned short*)d_out;
  // ws layout: Wb (fp16, 768*256 = 384 KB) | qkv (3 * 33554432 fp16 = 192 MB)
  unsigned short* Wb = (unsigned short*)d_ws;
  unsigned short* qkv = (unsigned short*)((char*)d_ws + 393216);

  prep<<<dim3(17152), dim3(256), 0, stream>>>(x, Wq, Wk, Wv, xh, Wb);
  qkv_gemm<<<dim3(6144), dim3(256), 0, stream>>>(xh, Wb, qkv);
  qrel<<<dim3(512), dim3(256), 0, stream>>>(qkv, relx, rely, qrl);
  attn<<<dim3(512), dim3(512), 0, stream>>>(qkv, bias, qrl, out);
}

// Round 10
// 271.772 us; speedup vs baseline: 1.0117x; 1.0117x over previous
//
#include <hip/hip_runtime.h>
#include <hip/hip_fp16.h>
#include <stdint.h>

// Problem constants: B=8, H=W=128, C=F=256, K=7, PAD=3, rs=128
typedef _Float16 half8 __attribute__((ext_vector_type(8)));   // 8 fp16 = 4 VGPR (MFMA A/B frag)
typedef _Float16 half2v __attribute__((ext_vector_type(2)));  // packed fp16 pair
typedef __attribute__((ext_vector_type(4))) float f32x4;      // MFMA C/D frag

__device__ __forceinline__ unsigned short f2h(float f) {      // RNE fp32->fp16
  __half h = __float2half(f);
  unsigned short u; __builtin_memcpy(&u, &h, 2); return u;
}
__device__ __forceinline__ unsigned pk2h(float a, float b) {  // RTZ packed pair (staging only)
  auto v = __builtin_amdgcn_cvt_pkrtz(a, b);
  unsigned u; __builtin_memcpy(&u, &v, 4); return u;
}
__device__ __forceinline__ half2v h2cast(unsigned u) {
  half2v v; __builtin_memcpy(&v, &u, 4); return v;
}

#if __has_builtin(__builtin_amdgcn_fdot2)
__device__ __forceinline__ float dot2(half2v a, half2v b, float c) {
  return __builtin_amdgcn_fdot2(a, b, c, false);
}
#else
__device__ __forceinline__ float dot2(half2v a, half2v b, float c) {
  return c + (float)a[0] * (float)b[0] + (float)a[1] * (float)b[1];
}
#endif

// async global->LDS, 16B per lane; lds dest = wave-uniform base + lane*16
__device__ __forceinline__ void gl_lds16(const void* g, void* l) {
  __builtin_amdgcn_global_load_lds(
      (const __attribute__((address_space(1))) void*)g,
      (__attribute__((address_space(3))) void*)l, 16, 0, 0);
}

// ---------------- Kernel 0+1 merged: x fp32->fp16, and weight transpose+cvt ----------
__global__ __launch_bounds__(256) void prep(const float* __restrict__ x,
                                            const float* __restrict__ Wq,
                                            const float* __restrict__ Wk,
                                            const float* __restrict__ Wv,
                                            unsigned short* __restrict__ xh,
                                            unsigned short* __restrict__ Wb) {
  const int bid = blockIdx.x;
  if (bid < 16384) {
    const size_t i = ((size_t)bid * 256 + threadIdx.x) * 8;
    float4 a = *(const float4*)&x[i];
    float4 b = *(const float4*)&x[i + 4];
    uint4 o;
    o.x = pk2h(a.x, a.y); o.y = pk2h(a.z, a.w);
    o.z = pk2h(b.x, b.y); o.w = pk2h(b.z, b.w);
    *(uint4*)&xh[i] = o;
  } else {
    const int e = bid - 16384;
    const int w = e >> 8;
    const int n = e & 255;
    const float* W = (w == 0) ? Wq : ((w == 1) ? Wk : Wv);
    const int k = threadIdx.x;
    Wb[(size_t)e * 256 + k] = f2h(W[(size_t)k * 256 + n]);
  }
}

// ---------------- Kernel 2: fused QKV GEMM (fp16 MFMA, global_load_lds staging) ----------
__global__ __launch_bounds__(256) void qkv_gemm(const unsigned short* __restrict__ xh,
                                                const unsigned short* __restrict__ Wb,
                                                unsigned short* __restrict__ qkv) {
  __shared__ unsigned char ldsb[32768];

  const int tid = threadIdx.x;
  const int l = tid & 63, l15 = l & 15, l4 = l >> 4;
  const int wv = tid >> 6, wr = wv >> 1, wc = wv & 1;

  // XCD-aware chunked swizzle: 6144 blocks, 8 XCDs, 768 per XCD (bijective).
  const int pid = blockIdx.x;
  const int cid = (pid & 7) * 768 + (pid >> 3);
  const int by = cid / 6;
  const int bx = cid - by * 6;
  const size_t row0 = (size_t)by * 128;
  const int n0 = bx * 128;

  const int rbase0 = wv * 32, rbase1 = wv * 32 + 16;
  const int rA0 = rbase0 + (l >> 2), rA1 = rbase1 + (l >> 2);
  const int q0 = (l & 3) ^ ((rA0 >> 1) & 3), q1 = (l & 3) ^ ((rA1 >> 1) & 3);
  const unsigned short* gA0 = xh + (row0 + rA0) * 256 + q0 * 8;
  const unsigned short* gA1 = xh + (row0 + rA1) * 256 + q1 * 8;
  const unsigned short* gB0 = Wb + (size_t)(n0 + rA0) * 256 + q0 * 8;
  const unsigned short* gB1 = Wb + (size_t)(n0 + rA1) * 256 + q1 * 8;

  f32x4 acc[4][4] = {};

  auto stage = [&](int s, int d) {
    gl_lds16(gA0 + s * 32, &ldsb[d * 8192 + rbase0 * 64]);
    gl_lds16(gA1 + s * 32, &ldsb[d * 8192 + rbase1 * 64]);
    gl_lds16(gB0 + s * 32, &ldsb[16384 + d * 8192 + rbase0 * 64]);
    gl_lds16(gB1 + s * 32, &ldsb[16384 + d * 8192 + rbase1 * 64]);
  };

  stage(0, 0);
  __syncthreads();

  for (int s = 0; s < 8; ++s) {
    const int d = s & 1;
    if (s < 7) stage(s + 1, d ^ 1);
    half8 af[4], bf[4];
#pragma unroll
    for (int m = 0; m < 4; ++m) {
      const int r = wr * 64 + m * 16 + l15;
      af[m] = *(const half8*)&ldsb[d * 8192 + r * 64 + ((l4 ^ ((r >> 1) & 3)) * 16)];
    }
#pragma unroll
    for (int n = 0; n < 4; ++n) {
      const int r = wc * 64 + n * 16 + l15;
      bf[n] = *(const half8*)&ldsb[16384 + d * 8192 + r * 64 + ((l4 ^ ((r >> 1) & 3)) * 16)];
    }
#pragma unroll
    for (int n = 0; n < 4; ++n)
#pragma unroll
      for (int m = 0; m < 4; ++m)
        acc[m][n] = __builtin_amdgcn_mfma_f32_16x16x32_f16(af[m], bf[n], acc[m][n], 0, 0, 0);
    __syncthreads();
  }

  // Epilogue: C/D mapping col=lane&15, row=(lane>>4)*4+reg (m89-verified)
#pragma unroll
  for (int m = 0; m < 4; ++m)
#pragma unroll
    for (int n = 0; n < 4; ++n) {
      const int ng = n0 + wc * 64 + n * 16 + l15;
      unsigned short* op = qkv + (size_t)(ng >> 8) * 33554432 + (ng & 255);
#pragma unroll
      for (int r = 0; r < 4; ++r) {
        const size_t grow = row0 + wr * 64 + m * 16 + l4 * 4 + r;
        op[grow * 256] = f2h(acc[m][n][r]);
      }
    }
}

// ---------------- Kernel 2b: per-pixel relative-position projections ----------------
__global__ __launch_bounds__(256) void qrel(const unsigned short* __restrict__ q,
                                            const float* __restrict__ relx,
                                            const float* __restrict__ rely,
                                            unsigned short* __restrict__ qr) {
  __shared__ unsigned wpk[896];  // [0..447] x-pairs, [448..895] y-pairs; wpk[c2*7+j]
  for (int i = threadIdx.x; i < 896; i += 256) {
    const int hf = (i >= 448) ? 1 : 0;
    const int r = i - hf * 448;
    const int c2 = r / 7, j = r - c2 * 7;
    const float* R = hf ? rely : relx;
    wpk[i] = pk2h(R[(2 * c2) * 7 + j], R[(2 * c2 + 1) * 7 + j]);
  }
  __syncthreads();
  const size_t pix = (size_t)blockIdx.x * 256 + threadIdx.x;
  const uint4* qp = (const uint4*)(q + pix * 256);  // 32 uint4 = 256 fp16 channels
  float ax[7] = {0, 0, 0, 0, 0, 0, 0}, ay[7] = {0, 0, 0, 0, 0, 0, 0};
#pragma unroll
  for (int g = 0; g < 32; ++g) {
    const uint4 u = qp[g];
    const int c2b = (g & 15) * 4;
    if (g < 16) {
#pragma unroll
      for (int j = 0; j < 7; ++j) {
        float s = ax[j];
        s = dot2(h2cast(u.x), h2cast(wpk[(c2b + 0) * 7 + j]), s);
        s = dot2(h2cast(u.y), h2cast(wpk[(c2b + 1) * 7 + j]), s);
        s = dot2(h2cast(u.z), h2cast(wpk[(c2b + 2) * 7 + j]), s);
        s = dot2(h2cast(u.w), h2cast(wpk[(c2b + 3) * 7 + j]), s);
        ax[j] = s;
      }
    } else {
#pragma unroll
      for (int j = 0; j < 7; ++j) {
        float s = ay[j];
        s = dot2(h2cast(u.x), h2cast(wpk[448 + (c2b + 0) * 7 + j]), s);
        s = dot2(h2cast(u.y), h2cast(wpk[448 + (c2b + 1) * 7 + j]), s);
        s = dot2(h2cast(u.z), h2cast(wpk[448 + (c2b + 2) * 7 + j]), s);
        s = dot2(h2cast(u.w), h2cast(wpk[448 + (c2b + 3) * 7 + j]), s);
        ay[j] = s;
      }
    }
  }
  uint4 o0, o1;
  o0.x = pk2h(ax[0], ax[1]); o0.y = pk2h(ax[2], ax[3]);
  o0.z = pk2h(ax[4], ax[5]); o0.w = pk2h(ax[6], ay[0]);
  o1.x = pk2h(ay[1], ay[2]); o1.y = pk2h(ay[3], ay[4]);
  o1.z = pk2h(ay[5], ay[6]); o1.w = 0;
  uint4* dst = (uint4*)(qr + pix * 512);
  dst[0] = o0; dst[1] = o1;
}

// ---------------- Kernel 3: fused windowed attention ----------------
// v11 = v10 + DEEPER dependent-chain batching (the only lever with measured gains).
// Falsified so far: barrier count (v3: 0), load-latency hiding (v3: 0), LDS traffic
// (v10: -43% traffic -> -2us), VALU volume (v10: 0), occupancy reshaping (v4/v7: neg).
// v9's depth-7 read batching: -7us. All pipes <=23% busy => intra-wave lgkmcnt stalls
// dominate with 2 waves/SIMD. So: widen the independent-instruction window.
//  * Phase B: halo rows processed in PAIRS - 14 b128 in flight before FMA (was 7).
//  * Phase A: all 14 K-frags (7 tiles x 2 groups) loaded before the 14-MFMA burst
//    (was interleaved at depth 2).
// Peak regs: phase A ~85 arch + 56 kf + 56 acc ~= 197 <= 256 cap (launch_bounds 512,2);
// phase B ~141. No spill expected. All else byte-identical to v10.
__global__ __launch_bounds__(512, 2) void attn(const unsigned short* __restrict__ qkv,
                                               const float* __restrict__ bias,
                                               const unsigned short* __restrict__ qrelb,
                                               float* __restrict__ out) {
  __shared__ unsigned short kv[2][4][4256];  // 2 buf x 4 planes x 532 slots*8 = 68096 B

  const int tid = threadIdx.x;               // 0..511
  const int wv = tid >> 6;                   // wave 0..7
  const int lo = tid & 15, hi = (tid >> 4) & 3;
  const int rp = wv >> 1;                    // phase-A row-pair 0..3
  const int ch16 = (wv & 1) * 16;            // phase-A column-half base

  // phase-B pair mapping
  const int q = tid >> 7;                    // plane-quarter 0..3 (ch q*8..q*8+7)
  const int pa = (tid >> 5) & 3;             // pair-row (pixel rows 2pa, 2pa+1)
  const int pc = tid & 31;                   // col

  const int pid = blockIdx.x;
  const int cid = (pid & 7) * 64 + (pid >> 3);   // XCD-chunked (512 = 8*64, bijective)
  const int ht = cid & 15, wt = (cid >> 4) & 3, b = cid >> 6;

  const int hA = ht * 8 + 2 * pa, wA = wt * 32 + pc;
  const size_t pixA = (size_t)((b * 128 + hA) * 128 + wA);
  const size_t pixB = pixA + 128;
  const int pxA = 2 * pa * 32 + pc;          // pixel index within tile
  const int pxB = pxA + 32;

  const unsigned short* qb = qkv;
  const unsigned short* kb = qkv + 33554432;
  const unsigned short* vb = qkv + 67108864;

  // staging geometry: 532 halo slots; thread covers slot tid, and tid+512 (<532)
  const int pr0 = tid / 38, pc0 = tid - pr0 * 38;
  const int gh0 = ht * 8 + pr0 - 3, gw0 = wt * 32 + pc0 - 3;
  const bool ok0 = ((unsigned)gh0 < 128u) && ((unsigned)gw0 < 128u);
  const long long go0 = ((long long)((b * 128 + gh0) * 128 + gw0)) * 256;  // shorts

  const int p1 = tid + 512;
  const int pr1 = p1 / 38, pc1 = p1 - pr1 * 38;
  const int gh1 = ht * 8 + pr1 - 3, gw1 = wt * 32 + pc1 - 3;
  const bool ok1 = (p1 < 532) && ((unsigned)gh1 < 128u) && ((unsigned)gw1 < 128u);
  const long long go1 = ((long long)((b * 128 + gh1) * 128 + gw1)) * 256;

  // async stage of chunk c (4 planes) into buffer d (no registers, no waits)
  auto stage = [&](const unsigned short* base, int c, int d) {
#pragma unroll
    for (int g = 0; g < 4; ++g) {
      if (ok0) gl_lds16(base + go0 + c * 32 + g * 8, &kv[d][g][wv * 512]);
      if (ok1) gl_lds16(base + go1 + c * 32 + g * 8, &kv[d][g][4096]);
    }
  };

  // zero OOB halo slots (both buffers); needed before phase A and again before phase B
  auto zero_oob = [&]() {
    const uint4 z = make_uint4(0u, 0u, 0u, 0u);
    for (int p = tid; p < 532; p += 512) {
      const int pr = p / 38, pcx = p - pr * 38;
      const int gh = ht * 8 + pr - 3, gw = wt * 32 + pcx - 3;
      if (!((unsigned)gh < 128u && (unsigned)gw < 128u)) {
#pragma unroll
        for (int d = 0; d < 2; ++d)
#pragma unroll
          for (int g = 0; g < 4; ++g)
            *(uint4*)&kv[d][g][p * 8] = z;
      }
    }
  };

  zero_oob();
  stage(kb, 0, 0);
  __syncthreads();   // implicit vmcnt(0): chunk-0 K staged + OOB zeros visible

  // ---- Phase A (MFMA, v8/v9-verified mapping): acc[g][t] = S[16q][16keys tile t] ----
  int slot0[7];
#pragma unroll
  for (int t = 0; t < 7; ++t) {
    const int p = t * 16 + lo;
    const int ur = p / 14, uc = p - ur * 14;
    slot0[t] = (2 * rp + ur) * 38 + ch16 + uc;
  }
  const size_t qpix =
      (size_t)((b * 128 + ht * 8 + 2 * rp + (lo >> 3)) * 128 + wt * 32 + ch16 + (lo & 7));
  const unsigned short* qlane = qb + qpix * 256 + hi * 8;

  f32x4 acc[2][7] = {};

  for (int s = 0; s < 8; ++s) {
    const int d = s & 1;
    if (s < 7) stage(kb, s + 1, d ^ 1);
    half8 qf[2];
#pragma unroll
    for (int g = 0; g < 2; ++g)
      qf[g] = *(const half8*)(qlane + (size_t)g * 2048 + s * 32);  // +8 px per group
    const unsigned short* kpl = &kv[d][hi][0];
    __builtin_amdgcn_s_setprio(1);
    // v11: batch ALL 14 K-frag reads before the MFMA burst (no per-tile lgkm waits)
    half8 kf[7][2];
#pragma unroll
    for (int t = 0; t < 7; ++t) {
      const unsigned short* kt = kpl + slot0[t] * 8;
      kf[t][0] = *(const half8*)(kt);
      kf[t][1] = *(const half8*)(kt + 64);
    }
#pragma unroll
    for (int t = 0; t < 7; ++t) {
      acc[0][t] = __builtin_amdgcn_mfma_f32_16x16x32_f16(qf[0], kf[t][0], acc[0][t], 0, 0, 0);
      acc[1][t] = __builtin_amdgcn_mfma_f32_16x16x32_f16(qf[1], kf[t][1], acc[1][t], 0, 0, 0);
    }
    __builtin_amdgcn_s_setprio(0);
    __syncthreads();
  }

  // ---- P hand-off: scatter valid-window scores (f32) into P-buffer aliasing kv ----
  float* pbuf = (float*)&kv[0][0][0];  // 256 rows x 52 f32 = 53248 B <= 68096 B
#pragma unroll
  for (int t = 0; t < 7; ++t) {
    const int p = t * 16 + lo;
    const int ur = p / 14, uc = p - ur * 14;
#pragma unroll
    for (int r = 0; r < 4; ++r) {
      const int qq = hi * 4 + r;
      const int di = ur - (qq >> 3), dj = uc - (qq & 7);
      if (((unsigned)di < 7u) && ((unsigned)dj < 7u)) {
        const int pslot = di * 7 + dj;
#pragma unroll
        for (int g = 0; g < 2; ++g) {
          const int prow_ = (2 * rp + (qq >> 3)) * 32 + ch16 + 8 * g + (qq & 7);
          pbuf[prow_ * 52 + pslot] = acc[g][t][r];
        }
      }
    }
  }
  __syncthreads();

  // ---- pair softmax: pixel A -> pwp low16, pixel B -> pwp high16 ----
  unsigned pwp[49];
  {
    float sc[49];
    const float* prow = pbuf + pxA * 52;
#pragma unroll
    for (int k = 0; k < 12; ++k) {
      const float4 v = ((const float4*)prow)[k];
      sc[k * 4 + 0] = v.x; sc[k * 4 + 1] = v.y;
      sc[k * 4 + 2] = v.z; sc[k * 4 + 3] = v.w;
    }
    sc[48] = prow[48];
    const uint4* rpq = (const uint4*)(qrelb + pixA * 512);
    uint4 r0 = rpq[0], r1 = rpq[1];
    half2v a0 = h2cast(r0.x), a1 = h2cast(r0.y), a2 = h2cast(r0.z), a3 = h2cast(r0.w);
    half2v b0 = h2cast(r1.x), b1 = h2cast(r1.y), b2 = h2cast(r1.z);
    float qx[7] = {a0[0], a0[1], a1[0], a1[1], a2[0], a2[1], a3[0]};
    float qy[7] = {a3[1], b0[0], b0[1], b1[0], b1[1], b2[0], b2[1]};
#pragma unroll
    for (int i = 0; i < 7; ++i)
#pragma unroll
      for (int j = 0; j < 7; ++j) sc[i * 7 + j] += qx[j] + qy[i];
    float mx = sc[0];
#pragma unroll
    for (int t = 1; t < 49; ++t) mx = fmaxf(mx, sc[t]);
    float sum = 0.0f;
#pragma unroll
    for (int t = 0; t < 49; ++t) {
      float e = __expf(sc[t] - mx);
      sc[t] = e;
      sum += e;
    }
    const float invs = 1.0f / sum;
#pragma unroll
    for (int t = 0; t < 49; ++t) pwp[t] = (unsigned)f2h(sc[t] * invs);
  }
  {
    float sc[49];
    const float* prow = pbuf + pxB * 52;
#pragma unroll
    for (int k = 0; k < 12; ++k) {
      const float4 v = ((const float4*)prow)[k];
      sc[k * 4 + 0] = v.x; sc[k * 4 + 1] = v.y;
      sc[k * 4 + 2] = v.z; sc[k * 4 + 3] = v.w;
    }
    sc[48] = prow[48];
    const uint4* rpq = (const uint4*)(qrelb + pixB * 512);
    uint4 r0 = rpq[0], r1 = rpq[1];
    half2v a0 = h2cast(r0.x), a1 = h2cast(r0.y), a2 = h2cast(r0.z), a3 = h2cast(r0.w);
    half2v b0 = h2cast(r1.x), b1 = h2cast(r1.y), b2 = h2cast(r1.z);
    float qx[7] = {a0[0], a0[1], a1[0], a1[1], a2[0], a2[1], a3[0]};
    float qy[7] = {a3[1], b0[0], b0[1], b1[0], b1[1], b2[0], b2[1]};
#pragma unroll
    for (int i = 0; i < 7; ++i)
#pragma unroll
      for (int j = 0; j < 7; ++j) sc[i * 7 + j] += qx[j] + qy[i];
    float mx = sc[0];
#pragma unroll
    for (int t = 1; t < 49; ++t) mx = fmaxf(mx, sc[t]);
    float sum = 0.0f;
#pragma unroll
    for (int t = 0; t < 49; ++t) {
      float e = __expf(sc[t] - mx);
      sc[t] = e;
      sum += e;
    }
    const float invs = 1.0f / sum;
#pragma unroll
    for (int t = 0; t < 49; ++t) pwp[t] |= ((unsigned)f2h(sc[t] * invs)) << 16;
  }
  __syncthreads();   // all pbuf reads done before kv is clobbered below

  // restore kv for phase B: re-zero OOB slots, stage V chunk 0 into buf 0
  zero_oob();
  stage(vb, 0, 0);
  __syncthreads();   // vmcnt(0): V chunk 0 + re-zeroed OOB visible

  // ---- Phase B (pair-shared, v11 row-pair batching): 2 px x 8 ch (plane q) ----
  for (int s = 0; s < 8; ++s) {
    const int d = s & 1;
    const int f0 = s * 32 + q * 8;
    if (s < 7) stage(vb, s + 1, d ^ 1);
    half2v accA[4], accB[4];
#pragma unroll
    for (int a2 = 0; a2 < 4; ++a2) {
      accA[a2] = half2v{(_Float16)0, (_Float16)0};
      accB[a2] = half2v{(_Float16)0, (_Float16)0};
    }
    __builtin_amdgcn_s_setprio(1);
#pragma unroll
    for (int ub = 0; ub < 4; ++ub) {   // halo row pair (2ub, 2ub+1) of the 8 shared rows
      const int u0 = 2 * ub, u1 = u0 + 1;
      const int r0b = ((2 * pa + u0) * 38 + pc) * 8;
      const int r1b = ((2 * pa + u1) * 38 + pc) * 8;
      uint4 ua[14];
#pragma unroll
      for (int j = 0; j < 7; ++j) {
        ua[j] = *(const uint4*)&kv[d][q][r0b + j * 8];
        ua[7 + j] = *(const uint4*)&kv[d][q][r1b + j * 8];
      }
      // row u0: A taps always (u0 in {0,2,4,6} < 7); B taps iff u0>=1 (ub>0)
#pragma unroll
      for (int j = 0; j < 7; ++j) {
        {
          const half2v pp = h2cast(pwp[u0 * 7 + j]);
          const half2v p2 = half2v{pp[0], pp[0]};
          accA[0] += p2 * h2cast(ua[j].x);
          accA[1] += p2 * h2cast(ua[j].y);
          accA[2] += p2 * h2cast(ua[j].z);
          accA[3] += p2 * h2cast(ua[j].w);
        }
        if (ub > 0) {
          const half2v pp = h2cast(pwp[(u0 - 1) * 7 + j]);
          const half2v p2 = half2v{pp[1], pp[1]};
          accB[0] += p2 * h2cast(ua[j].x);
          accB[1] += p2 * h2cast(ua[j].y);
          accB[2] += p2 * h2cast(ua[j].z);
          accB[3] += p2 * h2cast(ua[j].w);
        }
      }
      // row u1: A taps iff u1<7 (ub<3); B taps always (u1>=1)
#pragma unroll
      for (int j = 0; j < 7; ++j) {
        if (ub < 3) {
          const half2v pp = h2cast(pwp[u1 * 7 + j]);
          const half2v p2 = half2v{pp[0], pp[0]};
          accA[0] += p2 * h2cast(ua[7 + j].x);
          accA[1] += p2 * h2cast(ua[7 + j].y);
          accA[2] += p2 * h2cast(ua[7 + j].z);
          accA[3] += p2 * h2cast(ua[7 + j].w);
        }
        {
          const half2v pp = h2cast(pwp[(u1 - 1) * 7 + j]);
          const half2v p2 = half2v{pp[1], pp[1]};
          accB[0] += p2 * h2cast(ua[7 + j].x);
          accB[1] += p2 * h2cast(ua[7 + j].y);
          accB[2] += p2 * h2cast(ua[7 + j].z);
          accB[3] += p2 * h2cast(ua[7 + j].w);
        }
      }
    }
    __builtin_amdgcn_s_setprio(0);
#pragma unroll
    for (int fq = 0; fq < 2; ++fq) {
      float4 bv = *(const float4*)&bias[f0 + fq * 4];
      float4 oA, oB;
      oA.x = (float)accA[fq * 2 + 0][0] + bv.x;
      oA.y = (float)accA[fq * 2 + 0][1] + bv.y;
      oA.z = (float)accA[fq * 2 + 1][0] + bv.z;
      oA.w = (float)accA[fq * 2 + 1][1] + bv.w;
      oB.x = (float)accB[fq * 2 + 0][0] + bv.x;
      oB.y = (float)accB[fq * 2 + 0][1] + bv.y;
      oB.z = (float)accB[fq * 2 + 1][0] + bv.z;
      oB.w = (float)accB[fq * 2 + 1][1] + bv.w;
      *(float4*)&out[pixA * 256 + f0 + fq * 4] = oA;
      *(float4*)&out[pixB * 256 + f0 + fq * 4] = oB;
    }
    if (s < 7) __syncthreads();
  }
}

extern "C" void kernel_launch(void* const* d_in, const int* in_sizes, int n_in,
                              void* d_out, int out_size, void* d_ws, size_t ws_size,
                              hipStream_t stream) {
  const float* x = (const float*)d_in[0];
  const float* Wq = (const float*)d_in[1];
  const float* Wk = (const float*)d_in[2];
  const float* Wv = (const float*)d_in[3];
  const float* relx = (const float*)d_in[4];
  const float* rely = (const float*)d_in[5];
  const float* bias = (const float*)d_in[6];
  float* out = (float*)d_out;

  // d_out doubles as scratch: xh (fp16 x) dead after qkv_gemm; qrel writes 32 B into each
  // pixel's out slot head, read by attn before that slot is overwritten.
  unsigned short* xh = (unsigned short*)d_out;
  unsigned short* qrl = (unsigned short*)d_out;
  // ws layout: Wb (fp16, 768*256 = 384 KB) | qkv (3 * 33554432 fp16 = 192 MB)
  unsigned short* Wb = (unsigned short*)d_ws;
  unsigned short* qkv = (unsigned short*)((char*)d_ws + 393216);

  prep<<<dim3(17152), dim3(256), 0, stream>>>(x, Wq, Wk, Wv, xh, Wb);
  qkv_gemm<<<dim3(6144), dim3(256), 0, stream>>>(xh, Wb, qkv);
  qrel<<<dim3(512), dim3(256), 0, stream>>>(qkv, relx, rely, qrl);
  attn<<<dim3(512), dim3(512), 0, stream>>>(qkv, bias, qrl, out);
}